// Round 7
// baseline (1225.729 us; speedup 1.0000x reference)
//
#include <hip/hip_runtime.h>
#include <math.h>

// Problem constants (fixed by the reference): B=256, S=2048, I=32, H=128, O=1
#define B_ 256
#define S_ 2048
#define I_ 32
#define H_ 128

// Barrier WITHOUT vmcnt(0) drain (HIP __syncthreads waits vmcnt(0) before
// s_barrier, stalling on in-flight global prefetch/stores every step).
// LDS visibility only needs lgkmcnt(0).
__device__ __forceinline__ void sync_lds() {
    asm volatile("" ::: "memory");
    asm volatile("s_waitcnt lgkmcnt(0)" ::: "memory");
    __builtin_amdgcn_s_barrier();
    asm volatile("" ::: "memory");
}

// tanh(z) = 1 - 2/(e^{2z}+1); exact limits at +-inf, abs err ~1e-7.
__device__ __forceinline__ float fast_tanh(float z) {
    float e = __expf(2.0f * z);
    return 1.0f - 2.0f / (e + 1.0f);
}

template <int CTRL>
__device__ __forceinline__ float dppf(float v) {
    return __int_as_float(__builtin_amdgcn_update_dpp(
        0, __float_as_int(v), CTRL, 0xF, 0xF, false));
}
// DPP controls: 0xB1 = quad_perm [1,0,3,2] (xor1), 0x4E = quad_perm [2,3,0,1]
// (xor2), 0x124 = row_ror:4, 0x128 = row_ror:8.
// ror4+ror8 compose to an all-reduce over lane bits {2,3} within a 16-lane
// row while preserving bits {0,1}: v+=ror4(v); v+=ror8(v) -> every lane gets
// sum of the 4 lanes {L, L+4, L+8, L+12 (mod 16 in-row)}.

// Full-wave (64-lane) sum, VALU-only; result valid in lane 63. (fallback path)
__device__ __forceinline__ float dpp_red_sum64(float v) {
    float t;
    t = __int_as_float(__builtin_amdgcn_update_dpp(0, __float_as_int(v), 0x111, 0xf, 0xf, false)); v += t;
    t = __int_as_float(__builtin_amdgcn_update_dpp(0, __float_as_int(v), 0x112, 0xf, 0xf, false)); v += t;
    t = __int_as_float(__builtin_amdgcn_update_dpp(0, __float_as_int(v), 0x114, 0xf, 0xf, false)); v += t;
    t = __int_as_float(__builtin_amdgcn_update_dpp(0, __float_as_int(v), 0x118, 0xf, 0xf, false)); v += t;
    t = __int_as_float(__builtin_amdgcn_update_dpp(0, __float_as_int(v), 0x142, 0xa, 0xf, false)); v += t;
    t = __int_as_float(__builtin_amdgcn_update_dpp(0, __float_as_int(v), 0x143, 0xc, 0xf, false)); v += t;
    return v;
}

// ============================ MAIN PATH =================================
// rnn_main: 8 waves/batch, lane owns 8 k x 4 h (32 FMA, WhR[32]).
//   h0 read: 2 x ds_read_b128/lane (16 LDS instr/step total, was 32+).
//   k-reduce: xor1/xor2 (quad_perm + select; lane keeps h = hbase+2b0+b1),
//   then ror4+ror8 all-reduce over remaining k (lane bits 2,3). xw = x.Wi
//   split over the same duplicate bits {2,3} (8 FMA + ror4/ror8).
//   hn goes STRAIGHT TO GLOBAL (fire-and-forget; sync_lds never drains
//   vmcnt) -- no score/proj/wd work in the sequential kernel at all.
//   ONE barrier per step; LDS = 1 KB (double-buffered h0 only).
#define STEP_MAIN(s, XA, XB)                                                  \
  {                                                                           \
    const float4* hsrc = (const float4*)&h0_lds[(s) & 1][0];                  \
    float4 hv0 = hsrc[2 * kgl];                                               \
    float4 hv1 = hsrc[2 * kgl + 1];                                           \
    float a0 = 0.f, a1 = 0.f, a2 = 0.f, a3 = 0.f;                             \
    {                                                                         \
      const float* hvf = (const float*)&hv0;                                  \
      _Pragma("unroll")                                                       \
      for (int c = 0; c < 4; ++c) {                                           \
        float hval = hvf[c];                                                  \
        a0 = fmaf(hval, WhR[c * 4 + 0], a0);                                  \
        a1 = fmaf(hval, WhR[c * 4 + 1], a1);                                  \
        a2 = fmaf(hval, WhR[c * 4 + 2], a2);                                  \
        a3 = fmaf(hval, WhR[c * 4 + 3], a3);                                  \
      }                                                                       \
      const float* hvg = (const float*)&hv1;                                  \
      _Pragma("unroll")                                                       \
      for (int c = 0; c < 4; ++c) {                                           \
        float hval = hvg[c];                                                  \
        a0 = fmaf(hval, WhR[16 + c * 4 + 0], a0);                             \
        a1 = fmaf(hval, WhR[16 + c * 4 + 1], a1);                             \
        a2 = fmaf(hval, WhR[16 + c * 4 + 2], a2);                             \
        a3 = fmaf(hval, WhR[16 + c * 4 + 3], a3);                             \
      }                                                                       \
    }                                                                         \
    float d0 = dppf<0xB1>(a0), d1 = dppf<0xB1>(a1);                           \
    float d2 = dppf<0xB1>(a2), d3 = dppf<0xB1>(a3);                           \
    float v0 = (b0 ? a2 : a0) + (b0 ? d2 : d0);                               \
    float v1 = (b0 ? a3 : a1) + (b0 ? d3 : d1);                               \
    float e0 = dppf<0x4E>(v0), e1 = dppf<0x4E>(v1);                           \
    float uu = (b1 ? v1 : v0) + (b1 ? e1 : e0);                               \
    uu += dppf<0x124>(uu);                                                    \
    uu += dppf<0x128>(uu);                                                    \
    float xwp = biasR;                                                        \
    xwp = fmaf((XA).x, WiC[0], xwp);                                          \
    xwp = fmaf((XA).y, WiC[1], xwp);                                          \
    xwp = fmaf((XA).z, WiC[2], xwp);                                          \
    xwp = fmaf((XA).w, WiC[3], xwp);                                          \
    xwp = fmaf((XB).x, WiC[4], xwp);                                          \
    xwp = fmaf((XB).y, WiC[5], xwp);                                          \
    xwp = fmaf((XB).z, WiC[6], xwp);                                          \
    xwp = fmaf((XB).w, WiC[7], xwp);                                          \
    xwp += dppf<0x124>(xwp);                                                  \
    xwp += dppf<0x128>(xwp);                                                  \
    float hn = uu + xwp;                                                      \
    {   /* refill slot with x row s+2 (clamped, in-bounds, vmcnt-tracked) */  \
      const float4* xr = (const float4*)xrow;                                 \
      (XA) = xr[0]; (XB) = xr[1];                                             \
      if ((s) <= S_ - 4) xrow += I_;                                          \
    }                                                                         \
    float h0n;                                                                \
    if ((s) == 0)            { hstartR = hn; h0n = 0.0f; }                    \
    else if ((s) == S_ - 2)  { h0n = fast_tanh(hn + hstartR); }               \
    else if (rd == 1)        { h0n = fast_tanh(hn + h0R); }                   \
    else if (cnt == 0)       { h0n = fast_tanh(hn + htR); htR = hn; }         \
    else                     { h0n = fast_tanh(hn); }                         \
    h0R = h0n;                                                                \
    if (wmask) {                                                              \
      h0_lds[((s) + 1) & 1][hf] = h0n;                                        \
      hptr[(size_t)(s) * (B_ * H_)] = hn;                                     \
    }                                                                         \
    cnt = (cnt + 1 == rd) ? 0 : cnt + 1;                                      \
    sync_lds();                                                               \
  }

__global__ __launch_bounds__(512)
__attribute__((amdgpu_waves_per_eu(2, 2)))
void rnn_main(
    const float* __restrict__ x, const float* __restrict__ Wi,
    const float* __restrict__ bi, const float* __restrict__ Wh,
    const float* __restrict__ bh, const int* __restrict__ rdp,
    float* __restrict__ hid)
{
    const int b = blockIdx.x;
    const int t = threadIdx.x;
    const int w = t >> 6;             // wave 0..7, owns h [16w,16w+16)
    const int l = t & 63;
    const int  kgl   = l & 15;        // k-slice [8*kgl, 8*kgl+8)
    const int  hg    = (l >> 4) & 3;
    const int  hbase = 16 * w + 4 * hg;
    const bool b0    = l & 1;
    const bool b1    = (l >> 1) & 1;
    const int  hf    = hbase + 2 * (int)b0 + (int)b1;  // lane's final h
    const bool wmask = ((l & 0xC) == 0);  // 16 writer lanes (bits{2,3}==0)
    const int  i0x   = 8 * ((l >> 2) & 3);

    __shared__ __align__(16) float h0_lds[2][H_];

    const int rd = rdp[0];
    if (t < H_) h0_lds[0][t] = 0.0f;

    // Wh: WhR[c*4+hh] = Wh[(8*kgl+c)][hbase+hh]  (c<4 -> [0..16), c>=4 via +16)
    float WhR[32];
#pragma unroll
    for (int c = 0; c < 8; ++c) {
        float4 wv = *(const float4*)(Wh + (size_t)(8 * kgl + c) * H_ + hbase);
        int o = (c & 3) * 4 + (c >> 2) * 16;
        WhR[o + 0] = wv.x; WhR[o + 1] = wv.y; WhR[o + 2] = wv.z; WhR[o + 3] = wv.w;
    }
    // Wi: lane's 8-i slice of the column for hf
    float WiC[8];
#pragma unroll
    for (int i = 0; i < 8; ++i) WiC[i] = Wi[(size_t)(i0x + i) * H_ + hf];
    // bias added exactly once per hf: only on the bits{2,3}==0 duplicate
    const float biasR = wmask ? (bi[hf] + bh[hf]) : 0.0f;

    // x register pipeline: slot0 = even rows, slot1 = odd rows
    const float* xrow = x + (size_t)b * S_ * I_ + i0x;
    float4 xA0 = ((const float4*)xrow)[0];
    float4 xB0 = ((const float4*)xrow)[1];
    float4 xA1 = ((const float4*)(xrow + I_))[0];
    float4 xB1 = ((const float4*)(xrow + I_))[1];
    xrow += 2 * I_;   // -> row 2 (next prefetch target)

    float* hptr = hid + (size_t)b * H_ + hf;   // hid[(s*B + b)*H + h]

    sync_lds();

    float htR = 0.f, hstartR = 0.f, h0R = 0.f;
    int cnt = 0;  // s % rd, incremental

    for (int s = 0; s < S_; s += 2) {
        STEP_MAIN(s, xA0, xB0)
        STEP_MAIN(s + 1, xA1, xB1)
    }
}

// attn_main: block r handles flat chunk r = steps [8r,8r+8) x all b.
// p_{u,b} = hn . Wa ; q_{u,b} = hn . Wd[u*32768 + b*128 + :] ; then
// softmax over the 2048 (u,b) pairs; out[r] = bd + sum softmax*q.
// ba is softmax-invariant -> omitted.
__global__ __launch_bounds__(256) void attn_main(
    const float* __restrict__ hid, const float* __restrict__ Wa,
    const float* __restrict__ Wd, const float* __restrict__ bd,
    float* __restrict__ out)
{
    const int r = blockIdx.x;
    const int t = threadIdx.x;
    __shared__ __align__(16) float wa_s[H_];
    __shared__ float redm[4], redz[4], redw[4];
    if (t < H_) wa_s[t] = Wa[t];
    __syncthreads();

    float p[8], q[8];
    float mx = -1e30f;
#pragma unroll
    for (int u = 0; u < 8; ++u) {
        const float4* hp = (const float4*)(hid + ((size_t)(8 * r + u) * B_ + t) * H_);
        const float4* wp = (const float4*)(Wd + (size_t)u * (B_ * H_) + (size_t)t * H_);
        const float4* ap = (const float4*)wa_s;
        float pv = 0.f, qv = 0.f;
#pragma unroll 8
        for (int j = 0; j < 32; ++j) {
            float4 hv = hp[j];
            float4 av = ap[j];
            float4 wv = wp[j];
            pv = fmaf(hv.x, av.x, pv); pv = fmaf(hv.y, av.y, pv);
            pv = fmaf(hv.z, av.z, pv); pv = fmaf(hv.w, av.w, pv);
            qv = fmaf(hv.x, wv.x, qv); qv = fmaf(hv.y, wv.y, qv);
            qv = fmaf(hv.z, wv.z, qv); qv = fmaf(hv.w, wv.w, qv);
        }
        p[u] = pv; q[u] = qv;
        mx = fmaxf(mx, pv);
    }
#pragma unroll
    for (int off = 32; off > 0; off >>= 1) mx = fmaxf(mx, __shfl_xor(mx, off, 64));
    if ((t & 63) == 0) redm[t >> 6] = mx;
    __syncthreads();
    mx = fmaxf(fmaxf(redm[0], redm[1]), fmaxf(redm[2], redm[3]));
    float z = 0.f, wv = 0.f;
#pragma unroll
    for (int u = 0; u < 8; ++u) {
        float e = __expf(p[u] - mx);
        z += e;
        wv = fmaf(e, q[u], wv);
    }
#pragma unroll
    for (int off = 32; off > 0; off >>= 1) {
        z += __shfl_xor(z, off, 64);
        wv += __shfl_xor(wv, off, 64);
    }
    if ((t & 63) == 0) { redz[t >> 6] = z; redw[t >> 6] = wv; }
    __syncthreads();
    if (t == 0) {
        float Z = redz[0] + redz[1] + redz[2] + redz[3];
        float W = redw[0] + redw[1] + redw[2] + redw[3];
        out[r] = bd[0] + W / Z;
    }
}

// ============================ FALLBACK PATH (r6, proven) ==================
#define MACF1(hval, idx)                             \
    a0 = fmaf(hval, WhR[(idx) * 2 + 0], a0);         \
    a1 = fmaf(hval, WhR[(idx) * 2 + 1], a1);
#define MACF4(hv, j)                                 \
    MACF1((hv).x, 4 * (j) + 0)                       \
    MACF1((hv).y, 4 * (j) + 1)                       \
    MACF1((hv).z, 4 * (j) + 2)                       \
    MACF1((hv).w, 4 * (j) + 3)

#define STEP_FB(s, XA, XB)                                                    \
  {                                                                           \
    const float4* hsrc = (const float4*)&h0_lds[(s) & 1][0];                  \
    float4 hv0 = hsrc[kg];                                                    \
    float4 hv1 = hsrc[kg + 8];                                                \
    float4 hv2 = hsrc[kg + 16];                                               \
    float4 hv3 = hsrc[kg + 24];                                               \
    if ((s) > 0) {                                                            \
      if (w == 4) {                                                           \
        float2 hp = *(const float2*)&hn_lds[((s) - 1) & 1][2 * l];            \
        float pv = fmaf(hp.x, waR0, hp.y * waR1);                             \
        pv = dpp_red_sum64(pv);                                               \
        if (l == 63) ((float*)part)[((((s) - 1) << 8) + b) * 2] = pv;         \
      } else if (w == 6) {                                                    \
        float2 hp = *(const float2*)&hn_lds[((s) - 1) & 1][2 * l];            \
        float2 wdp = *(const float2*)&wd_lds[((((s) - 1) & 7) << 7) + 2 * l]; \
        float qv = fmaf(hp.x, wdp.x, hp.y * wdp.y);                           \
        qv = dpp_red_sum64(qv);                                               \
        if (l == 63) ((float*)part)[((((s) - 1) << 8) + b) * 2 + 1] = qv;     \
      }                                                                       \
    }                                                                         \
    float a0 = 0.f, a1 = 0.f;                                                 \
    MACF4(hv0, 0) MACF4(hv1, 1) MACF4(hv2, 2) MACF4(hv3, 3)                   \
    float d0 = dppf<0xB1>(a0), d1 = dppf<0xB1>(a1);                           \
    float acc = (kb0b ? a1 : a0) + (kb0b ? d1 : d0);                          \
    acc += dppf<0x4E>(acc);                                                   \
    acc += dppf<0x128>(acc);                                                  \
    float xwp = biasR;                                                        \
    xwp = fmaf((XA).x, WiC[0], xwp);                                          \
    xwp = fmaf((XA).y, WiC[1], xwp);                                          \
    xwp = fmaf((XA).z, WiC[2], xwp);                                          \
    xwp = fmaf((XA).w, WiC[3], xwp);                                          \
    xwp = fmaf((XB).x, WiC[4], xwp);                                          \
    xwp = fmaf((XB).y, WiC[5], xwp);                                          \
    xwp = fmaf((XB).z, WiC[6], xwp);                                          \
    xwp = fmaf((XB).w, WiC[7], xwp);                                          \
    xwp += dppf<0x4E>(xwp);                                                   \
    xwp += dppf<0x128>(xwp);                                                  \
    float hn = acc + xwp;                                                     \
    {                                                                         \
      const float4* xr = (const float4*)xrow;                                 \
      (XA) = xr[0]; (XB) = xr[1];                                             \
      if ((s) <= S_ - 4) xrow += I_;                                          \
    }                                                                         \
    float h0n;                                                                \
    if ((s) == 0)            { hstartR = hn; h0n = 0.0f; }                    \
    else if ((s) == S_ - 2)  { h0n = fast_tanh(hn + hstartR); }               \
    else if (rd == 1)        { h0n = fast_tanh(hn + h0R); }                   \
    else if (cnt == 0)       { h0n = fast_tanh(hn + htR); htR = hn; }         \
    else                     { h0n = fast_tanh(hn); }                         \
    h0R = h0n;                                                                \
    if (wmask) {                                                              \
      h0_lds[((s) + 1) & 1][hf] = h0n;                                        \
      hn_lds[(s) & 1][hf] = hn;                                               \
    }                                                                         \
    cnt = (cnt + 1 == rd) ? 0 : cnt + 1;                                      \
    sync_lds();                                                               \
  }

__global__ __launch_bounds__(512)
__attribute__((amdgpu_waves_per_eu(2, 2)))
void rnn_fb(
    const float* __restrict__ x, const float* __restrict__ Wi,
    const float* __restrict__ bi, const float* __restrict__ Wh,
    const float* __restrict__ bh, const float* __restrict__ Wa,
    const float* __restrict__ Wd, const int* __restrict__ rdp,
    float2* __restrict__ part)
{
    const int b = blockIdx.x;
    const int t = threadIdx.x;
    const int w = t >> 6;
    const int l = t & 63;
    const int  kg    = (l & 3) | (((l >> 3) & 1) << 2);
    const int  hg    = ((l >> 2) & 1) | (((l >> 4) & 1) << 1)
                     | (((l >> 5) & 1) << 2);
    const int  hbase = 16 * w + 2 * hg;
    const int  hf    = hbase + (l & 1);
    const bool kb0b  = (l & 1);
    const bool wmask = ((l & 0xA) == 0);
    const int  i0x   = 8 * (((l >> 1) & 1) | (((l >> 3) & 1) << 1));

    __shared__ __align__(16) float h0_lds[2][H_];
    __shared__ __align__(16) float hn_lds[2][H_];
    __shared__ __align__(16) float wd_lds[8 * H_];

    const int rd = rdp[0];
    for (int j = t; j < 8 * H_; j += 512)
        wd_lds[j] = Wd[((j >> 7) << 15) + (b << 7) + (j & 127)];
    if (t < H_) h0_lds[0][t] = 0.0f;

    float WhR[32];
#pragma unroll
    for (int j = 0; j < 4; ++j)
#pragma unroll
        for (int c = 0; c < 4; ++c) {
            int k = 4 * kg + 32 * j + c;
            float2 wvv = *(const float2*)(Wh + (size_t)k * H_ + hbase);
            WhR[(4 * j + c) * 2 + 0] = wvv.x;
            WhR[(4 * j + c) * 2 + 1] = wvv.y;
        }
    float WiC[8];
#pragma unroll
    for (int i = 0; i < 8; ++i) WiC[i] = Wi[(size_t)(i0x + i) * H_ + hf];
    const float biasR = wmask ? (bi[hf] + bh[hf]) : 0.0f;
    const float waR0 = Wa[2 * l], waR1 = Wa[2 * l + 1];

    const float* xrow = x + (size_t)b * S_ * I_ + i0x;
    float4 xA0 = ((const float4*)xrow)[0];
    float4 xB0 = ((const float4*)xrow)[1];
    float4 xA1 = ((const float4*)(xrow + I_))[0];
    float4 xB1 = ((const float4*)(xrow + I_))[1];
    xrow += 2 * I_;

    sync_lds();

    float htR = 0.f, hstartR = 0.f, h0R = 0.f;
    int cnt = 0;

    for (int s = 0; s < S_; s += 2) {
        STEP_FB(s, xA0, xB0)
        STEP_FB(s + 1, xA1, xB1)
    }

    if (w == 4) {
        float2 hp = *(const float2*)&hn_lds[(S_ - 1) & 1][2 * l];
        float pv = fmaf(hp.x, waR0, hp.y * waR1);
        pv = dpp_red_sum64(pv);
        if (l == 63) ((float*)part)[(((S_ - 1) << 8) + b) * 2] = pv;
    } else if (w == 6) {
        float2 hp = *(const float2*)&hn_lds[(S_ - 1) & 1][2 * l];
        float2 wdp = *(const float2*)&wd_lds[(((S_ - 1) & 7) << 7) + 2 * l];
        float qv = fmaf(hp.x, wdp.x, hp.y * wdp.y);
        qv = dpp_red_sum64(qv);
        if (l == 63) ((float*)part)[(((S_ - 1) << 8) + b) * 2 + 1] = qv;
    }
}

__global__ __launch_bounds__(256) void attn_fb(
    const float2* __restrict__ part, const float* __restrict__ bd,
    float* __restrict__ out)
{
    const int r = blockIdx.x;
    const int t = threadIdx.x;
    float sc[8], dv[8];
    float mx = -1e30f;
#pragma unroll
    for (int u = 0; u < 8; ++u) {
        int f = (r << 11) + (u << 8) + t;
        float2 a = part[f];
        sc[u] = a.x;
        dv[u] = a.y;
        mx = fmaxf(mx, sc[u]);
    }
    __shared__ float redm[4], redz[4], redw[4];
#pragma unroll
    for (int off = 32; off > 0; off >>= 1) mx = fmaxf(mx, __shfl_xor(mx, off, 64));
    if ((t & 63) == 0) redm[t >> 6] = mx;
    __syncthreads();
    mx = fmaxf(fmaxf(redm[0], redm[1]), fmaxf(redm[2], redm[3]));
    float z = 0.f, wv = 0.f;
#pragma unroll
    for (int u = 0; u < 8; ++u) {
        float e = __expf(sc[u] - mx);
        z += e;
        wv += e * dv[u];
    }
#pragma unroll
    for (int off = 32; off > 0; off >>= 1) {
        z += __shfl_xor(z, off, 64);
        wv += __shfl_xor(wv, off, 64);
    }
    if ((t & 63) == 0) { redz[t >> 6] = z; redw[t >> 6] = wv; }
    __syncthreads();
    if (t == 0) {
        float Z = redz[0] + redz[1] + redz[2] + redz[3];
        float W = redw[0] + redw[1] + redw[2] + redw[3];
        out[r] = bd[0] + W / Z;
    }
}

extern "C" void kernel_launch(void* const* d_in, const int* in_sizes, int n_in,
                              void* d_out, int out_size, void* d_ws, size_t ws_size,
                              hipStream_t stream) {
    const float* x  = (const float*)d_in[0];
    const float* Wi = (const float*)d_in[1];
    const float* bi = (const float*)d_in[2];
    const float* Wh = (const float*)d_in[3];
    const float* bh = (const float*)d_in[4];
    const float* Wa = (const float*)d_in[5];
    // d_in[6] = ba: constant shift inside each softmax chunk -> no effect.
    const float* Wd = (const float*)d_in[7];
    const float* bd = (const float*)d_in[8];
    const int*  rdp = (const int*)d_in[9];

    const size_t hid_bytes = (size_t)S_ * B_ * H_ * sizeof(float);  // 256 MiB
    if (ws_size >= hid_bytes) {
        float* hid = (float*)d_ws;
        rnn_main<<<B_, 512, 0, stream>>>(x, Wi, bi, Wh, bh, rdp, hid);
        attn_main<<<B_, 256, 0, stream>>>(hid, Wa, Wd, bd, (float*)d_out);
    } else {
        float2* part = (float2*)d_ws;   // 4 MiB
        rnn_fb<<<B_, 512, 0, stream>>>(x, Wi, bi, Wh, bh, Wa, Wd, rdp, part);
        attn_fb<<<B_, 256, 0, stream>>>(part, bd, (float*)d_out);
    }
}